// Round 2
// baseline (5377.835 us; speedup 1.0000x reference)
//
#include <hip/hip_runtime.h>

typedef unsigned int uint;

// ---------------- dense part ----------------

// AB[N][256]: cols 0..127 = x@Wa, cols 128..255 = x@Wb   (x fp32 [N][256], W fp32 [256][128])
#define BM 64
#define BN 128
#define BK 32
__global__ __launch_bounds__(256) void gemm_kernel(const float* __restrict__ x,
                                                   const float* __restrict__ Wa,
                                                   const float* __restrict__ Wb,
                                                   float* __restrict__ AB, int N) {
    __shared__ float xsT[BK][BM + 4];   // transposed x tile
    __shared__ float wsm[BK][BN];
    int t = threadIdx.x;
    int rowbase = blockIdx.x * BM;
    const float* W = (blockIdx.y == 0) ? Wa : Wb;
    int nb = blockIdx.y * BN;           // output column base
    int tx = t & 15, ty = t >> 4;       // 16 x 16 threads, 4 x 8 microtile
    float acc[4][8];
    #pragma unroll
    for (int i = 0; i < 4; i++)
        #pragma unroll
        for (int j = 0; j < 8; j++) acc[i][j] = 0.f;

    for (int k0 = 0; k0 < 256; k0 += BK) {
        {   // x tile: 64 rows x 32 k
            int r = t & 63;
            int koff = (t >> 6) * 8;
            int gr = rowbase + r; if (gr >= N) gr = N - 1;
            const float* src = x + (size_t)gr * 256 + k0 + koff;
            float4 u0 = *(const float4*)(src);
            float4 u1 = *(const float4*)(src + 4);
            xsT[koff + 0][r] = u0.x; xsT[koff + 1][r] = u0.y;
            xsT[koff + 2][r] = u0.z; xsT[koff + 3][r] = u0.w;
            xsT[koff + 4][r] = u1.x; xsT[koff + 5][r] = u1.y;
            xsT[koff + 6][r] = u1.z; xsT[koff + 7][r] = u1.w;
        }
        {   // W tile: 32 x 128 f32 = 1024 float4 / 256 threads
            #pragma unroll
            for (int i = 0; i < 4; i++) {
                int f = t + i * 256;
                int rr = f >> 5, c4 = f & 31;
                *(float4*)&wsm[rr][c4 * 4] =
                    *(const float4*)&W[(size_t)(k0 + rr) * 128 + c4 * 4];
            }
        }
        __syncthreads();
        #pragma unroll
        for (int kk = 0; kk < BK; ++kk) {
            float4 a  = *(const float4*)&xsT[kk][ty * 4];
            float4 b0 = *(const float4*)&wsm[kk][tx * 8];
            float4 b1 = *(const float4*)&wsm[kk][tx * 8 + 4];
            float av[4] = {a.x, a.y, a.z, a.w};
            float bv[8] = {b0.x, b0.y, b0.z, b0.w, b1.x, b1.y, b1.z, b1.w};
            #pragma unroll
            for (int i = 0; i < 4; i++)
                #pragma unroll
                for (int j = 0; j < 8; j++)
                    acc[i][j] = fmaf(av[i], bv[j], acc[i][j]);
        }
        __syncthreads();
    }
    #pragma unroll
    for (int i = 0; i < 4; i++) {
        int gr = rowbase + ty * 4 + i;
        if (gr < N) {
            float4 o0 = {acc[i][0], acc[i][1], acc[i][2], acc[i][3]};
            float4 o1 = {acc[i][4], acc[i][5], acc[i][6], acc[i][7]};
            *(float4*)&AB[(size_t)gr * 256 + nb + tx * 8]     = o0;
            *(float4*)&AB[(size_t)gr * 256 + nb + tx * 8 + 4] = o1;
        }
    }
}

// attention: P[n] = att0 * a + att1 * al ; one wave per node, 4 nodes/block
__global__ __launch_bounds__(256) void attn_kernel(const float* __restrict__ AB,
        const float* __restrict__ w1, const float* __restrict__ b1,
        const float* __restrict__ w2, float* __restrict__ P, int N) {
    __shared__ float w1s[128 * 32];
    __shared__ float b1s[32], w2s[32];
    __shared__ float aS[4][128], alS[4][128];
    int t = threadIdx.x;
    #pragma unroll
    for (int i = 0; i < 16; i++) w1s[t + i * 256] = w1[t + i * 256];
    if (t < 32) { b1s[t] = b1[t]; w2s[t] = w2[t]; }

    int w = t >> 6, lane = t & 63;
    int node = blockIdx.x * 4 + w;
    bool active = node < N;
    int nclamp = active ? node : (N - 1);
    float2 a = *(const float2*)(AB + (size_t)nclamp * 256 + lane * 2);
    float2 b = *(const float2*)(AB + (size_t)nclamp * 256 + 128 + lane * 2);
    float2 al;
    al.x = a.x + 0.5f * (a.x * a.x - a.x * b.x);
    al.y = a.y + 0.5f * (a.y * a.y - a.y * b.y);
    aS[w][lane * 2] = a.x;   aS[w][lane * 2 + 1] = a.y;
    alS[w][lane * 2] = al.x; alS[w][lane * 2 + 1] = al.y;
    __syncthreads();

    int j = lane & 31;
    const float* src = (lane < 32) ? aS[w] : alS[w];
    float acc = b1s[j];
    #pragma unroll 8
    for (int d = 0; d < 128; ++d) acc = fmaf(src[d], w1s[d * 32 + j], acc);
    float h = tanhf(acc);
    float prod = h * w2s[j];
    #pragma unroll
    for (int off = 1; off < 32; off <<= 1) prod += __shfl_xor(prod, off);
    float eo = __shfl_xor(prod, 32);
    float e0 = (lane < 32) ? prod : eo;
    float e1 = (lane < 32) ? eo : prod;
    float m = fmaxf(e0, e1);
    float p0 = expf(e0 - m), p1 = expf(e1 - m);
    float inv = 1.0f / (p0 + p1);
    float at0 = p0 * inv, at1 = p1 * inv;
    if (active) {
        float2 Pv;
        Pv.x = at0 * a.x + at1 * al.x;
        Pv.y = at0 * a.y + at1 * al.y;
        *(float2*)(P + (size_t)node * 128 + lane * 2) = Pv;
    }
}

// ---------------- CSR build ----------------

__global__ void hist_kernel(const int* __restrict__ r, int* __restrict__ cnt, int E) {
    int e = blockIdx.x * 256 + threadIdx.x;
    if (e < E) atomicAdd(&cnt[r[e]], 1);
}

// single-block hierarchical exclusive scan; cnt may alias curOut
__global__ __launch_bounds__(1024) void scan_kernel(const int* __restrict__ cnt,
        int* __restrict__ ptrOut, int* __restrict__ curOut, int n) {
    __shared__ int wsums[16];
    __shared__ int runbase_s;
    int t = threadIdx.x, lane = t & 63, wid = t >> 6;
    if (t == 0) runbase_s = 0;
    __syncthreads();
    for (int base = 0; base < n; base += 1024) {
        int idx = base + t;
        int v = (idx < n) ? cnt[idx] : 0;
        int x = v;
        #pragma unroll
        for (int off = 1; off < 64; off <<= 1) {
            int y = __shfl_up(x, off);
            if (lane >= off) x += y;
        }
        if (lane == 63) wsums[wid] = x;
        __syncthreads();
        int rb = runbase_s;
        __syncthreads();
        if (t == 0) {
            int a = 0;
            #pragma unroll
            for (int i = 0; i < 16; i++) { int bb = wsums[i]; wsums[i] = a; a += bb; }
            runbase_s = rb + a;
        }
        __syncthreads();
        int excl = rb + wsums[wid] + x - v;
        if (idx < n) { ptrOut[idx] = excl; curOut[idx] = excl; }
        __syncthreads();
    }
    if (t == 0) ptrOut[n] = runbase_s;
}

__global__ void fill_kernel(const int* __restrict__ r, const int* __restrict__ c,
        const float* __restrict__ v, int* __restrict__ cur, int2* __restrict__ pk, int E) {
    int e = blockIdx.x * 256 + threadIdx.x;
    if (e >= E) return;
    int rr = r[e];
    int pos = atomicAdd(&cur[rr], 1);
    pk[pos] = make_int2(c[e], __float_as_int(v[e]));
}

// ---------------- SpMM (row-per-wave gather) ----------------

__global__ __launch_bounds__(256) void spmm_single(const int* __restrict__ rp,
        const int2* __restrict__ pk, const float* __restrict__ X,
        float* __restrict__ out, float scale, int accum, int N) {
    int gt = blockIdx.x * 256 + threadIdx.x;
    int row = gt >> 6, lane = gt & 63;
    if (row >= N) return;
    int beg = rp[row], end = rp[row + 1];
    float ax = 0.f, ay = 0.f;
    for (int e = beg; e < end; ++e) {
        int2 cv = pk[e];
        float val = __int_as_float(cv.y);
        float2 xv = *(const float2*)(X + ((size_t)cv.x << 7) + (lane << 1));
        ax = fmaf(val, xv.x, ax);
        ay = fmaf(val, xv.y, ay);
    }
    size_t o = ((size_t)row << 7) + (lane << 1);
    float rx = scale * ax, ry = scale * ay;
    if (accum) { float2 prev = *(const float2*)(out + o); rx += prev.x; ry += prev.y; }
    *(float2*)(out + o) = make_float2(rx, ry);
}

// out (mode 0) / out -= (mode 1) :  0.5 * ((sum v*x)^2 - sum v*x^2)   per element
__global__ __launch_bounds__(256) void spmm_bp(const int* __restrict__ rp,
        const int2* __restrict__ pk, const float* __restrict__ X,
        float* __restrict__ out, int sub, int N) {
    int gt = blockIdx.x * 256 + threadIdx.x;
    int row = gt >> 6, lane = gt & 63;
    if (row >= N) return;
    int beg = rp[row], end = rp[row + 1];
    float sx = 0.f, sy = 0.f, qx = 0.f, qy = 0.f;
    for (int e = beg; e < end; ++e) {
        int2 cv = pk[e];
        float val = __int_as_float(cv.y);
        float2 xv = *(const float2*)(X + ((size_t)cv.x << 7) + (lane << 1));
        sx = fmaf(val, xv.x, sx);
        sy = fmaf(val, xv.y, sy);
        qx = fmaf(val * xv.x, xv.x, qx);
        qy = fmaf(val * xv.y, xv.y, qy);
    }
    float bx = 0.5f * (sx * sx - qx);
    float by = 0.5f * (sy * sy - qy);
    size_t o = ((size_t)row << 7) + (lane << 1);
    if (sub) {
        float2 prev = *(const float2*)(out + o);
        bx = prev.x - bx; by = prev.y - by;
    }
    *(float2*)(out + o) = make_float2(bx, by);
}

// ---------------- epilogue ----------------

__global__ void relu_kernel(const float* __restrict__ a, float* __restrict__ o, size_t n) {
    size_t i = ((size_t)blockIdx.x * 256 + threadIdx.x) * 4;
    if (i >= n) return;
    float4 v = *(const float4*)(a + i);
    float4 r;
    r.x = fmaxf(v.x, 0.f); r.y = fmaxf(v.y, 0.f);
    r.z = fmaxf(v.z, 0.f); r.w = fmaxf(v.w, 0.f);
    *(float4*)(o + i) = r;
}

// ---------------- launch ----------------

extern "C" void kernel_launch(void* const* d_in, const int* in_sizes, int n_in,
                              void* d_out, int out_size, void* d_ws, size_t ws_size,
                              hipStream_t stream) {
    (void)n_in; (void)out_size; (void)ws_size;
    const float* x   = (const float*)d_in[0];
    const float* Wa  = (const float*)d_in[1];
    const float* Wb  = (const float*)d_in[2];
    const float* w1  = (const float*)d_in[4];
    const float* b1  = (const float*)d_in[5];
    const float* w2  = (const float*)d_in[6];
    const int* rows  = (const int*)d_in[7];
    const int* cols  = (const int*)d_in[8];
    const float* vals = (const float*)d_in[9];
    float* out = (float*)d_out;

    const int N = in_sizes[0] / 256;
    const int E = in_sizes[7] / 7;
    const size_t NF = (size_t)N * 128;

    float* ws   = (float*)d_ws;
    float* AB   = ws;               // [N][256]  (regions 0+1; dead after attn)
    float* tbuf = ws;               // region 0 reuse: bilinear temp
    float* P    = ws + 2 * NF;      // region 2
    float* oacc = ws + 3 * NF;      // region 3
    int2*  pk   = (int2*)(ws + 4 * NF);    // E entries
    int*   rp   = (int*)(pk + E);          // N+1
    int*   cur  = rp + (N + 1);            // N

    dim3 b256(256);
    int egrid = (E + 255) / 256;
    int sgrid = (int)(((size_t)N * 64 + 255) / 256);
    int vgrid = (int)((NF / 4 + 255) / 256);

    // dense front-end
    dim3 ggrid((N + BM - 1) / BM, 2);
    gemm_kernel<<<ggrid, b256, 0, stream>>>(x, Wa, Wb, AB, N);
    attn_kernel<<<(N + 3) / 4, b256, 0, stream>>>(AB, w1, b1, w2, P, N);

    auto build = [&](int s) {
        hipMemsetAsync(cur, 0, (size_t)N * sizeof(int), stream);
        hist_kernel<<<egrid, b256, 0, stream>>>(rows + (size_t)s * E, cur, E);
        scan_kernel<<<1, 1024, 0, stream>>>(cur, rp, cur, N);
        fill_kernel<<<egrid, b256, 0, stream>>>(rows + (size_t)s * E, cols + (size_t)s * E,
                                                vals + (size_t)s * E, cur, pk, E);
    };

    // out_gcn: 0.5 * spmm(0, P)
    build(0);
    spmm_single<<<sgrid, b256, 0, stream>>>(rp, pk, P, oacc, 0.5f, 0, N);

    // t1 = bp(1) - bp(3); oacc += 0.25 * spmm(5, t1)
    build(1);
    spmm_bp<<<sgrid, b256, 0, stream>>>(rp, pk, P, tbuf, 0, N);
    build(3);
    spmm_bp<<<sgrid, b256, 0, stream>>>(rp, pk, P, tbuf, 1, N);
    build(5);
    spmm_single<<<sgrid, b256, 0, stream>>>(rp, pk, tbuf, oacc, 0.25f, 1, N);

    // t2 = bp(2) - bp(4); oacc += 0.25 * spmm(6, t2)
    build(2);
    spmm_bp<<<sgrid, b256, 0, stream>>>(rp, pk, P, tbuf, 0, N);
    build(4);
    spmm_bp<<<sgrid, b256, 0, stream>>>(rp, pk, P, tbuf, 1, N);
    build(6);
    spmm_single<<<sgrid, b256, 0, stream>>>(rp, pk, tbuf, oacc, 0.25f, 1, N);

    relu_kernel<<<vgrid, b256, 0, stream>>>(oacc, out, NF);
}

// Round 3
// 3394.878 us; speedup vs baseline: 1.5841x; 1.5841x over previous
//
#include <hip/hip_runtime.h>

typedef unsigned int uint;

__device__ __forceinline__ float bfl(uint u){ return __uint_as_float(u << 16); }
__device__ __forceinline__ float bfh(uint u){ return __uint_as_float(u & 0xFFFF0000u); }
__device__ __forceinline__ uint f2bfbits(float f){
    uint b = __float_as_uint(f);
    return (b + 0x7FFFu + ((b >> 16) & 1u)) >> 16;
}
__device__ __forceinline__ uint packbf2(float a, float b){
    return f2bfbits(a) | (f2bfbits(b) << 16);
}
__device__ __forceinline__ int smap(int4 m, int s){
    return (s == 0) ? m.x : (s == 1) ? m.y : (s == 2) ? m.z : m.w;
}

// ---------------- dense part ----------------

#define BM 64
#define BN 128
#define BK 32
__global__ __launch_bounds__(256) void gemm_kernel(const float* __restrict__ x,
                                                   const float* __restrict__ Wa,
                                                   const float* __restrict__ Wb,
                                                   float* __restrict__ AB, int N) {
    __shared__ float xsT[BK][BM + 4];
    __shared__ float wsm[BK][BN];
    int t = threadIdx.x;
    int rowbase = blockIdx.x * BM;
    const float* W = (blockIdx.y == 0) ? Wa : Wb;
    int nb = blockIdx.y * BN;
    int tx = t & 15, ty = t >> 4;
    float acc[4][8];
    #pragma unroll
    for (int i = 0; i < 4; i++)
        #pragma unroll
        for (int j = 0; j < 8; j++) acc[i][j] = 0.f;

    for (int k0 = 0; k0 < 256; k0 += BK) {
        {
            int r = t & 63;
            int koff = (t >> 6) * 8;
            int gr = rowbase + r; if (gr >= N) gr = N - 1;
            const float* src = x + (size_t)gr * 256 + k0 + koff;
            float4 u0 = *(const float4*)(src);
            float4 u1 = *(const float4*)(src + 4);
            xsT[koff + 0][r] = u0.x; xsT[koff + 1][r] = u0.y;
            xsT[koff + 2][r] = u0.z; xsT[koff + 3][r] = u0.w;
            xsT[koff + 4][r] = u1.x; xsT[koff + 5][r] = u1.y;
            xsT[koff + 6][r] = u1.z; xsT[koff + 7][r] = u1.w;
        }
        {
            #pragma unroll
            for (int i = 0; i < 4; i++) {
                int f = t + i * 256;
                int rr = f >> 5, c4 = f & 31;
                *(float4*)&wsm[rr][c4 * 4] =
                    *(const float4*)&W[(size_t)(k0 + rr) * 128 + c4 * 4];
            }
        }
        __syncthreads();
        #pragma unroll
        for (int kk = 0; kk < BK; ++kk) {
            float4 a  = *(const float4*)&xsT[kk][ty * 4];
            float4 b0 = *(const float4*)&wsm[kk][tx * 8];
            float4 b1 = *(const float4*)&wsm[kk][tx * 8 + 4];
            float av[4] = {a.x, a.y, a.z, a.w};
            float bv[8] = {b0.x, b0.y, b0.z, b0.w, b1.x, b1.y, b1.z, b1.w};
            #pragma unroll
            for (int i = 0; i < 4; i++)
                #pragma unroll
                for (int j = 0; j < 8; j++)
                    acc[i][j] = fmaf(av[i], bv[j], acc[i][j]);
        }
        __syncthreads();
    }
    #pragma unroll
    for (int i = 0; i < 4; i++) {
        int gr = rowbase + ty * 4 + i;
        if (gr < N) {
            float4 o0 = {acc[i][0], acc[i][1], acc[i][2], acc[i][3]};
            float4 o1 = {acc[i][4], acc[i][5], acc[i][6], acc[i][7]};
            *(float4*)&AB[(size_t)gr * 256 + nb + tx * 8]     = o0;
            *(float4*)&AB[(size_t)gr * 256 + nb + tx * 8 + 4] = o1;
        }
    }
}

// attention: Pb[n] packed bf16 [N][128]
__global__ __launch_bounds__(256) void attn_kernel(const float* __restrict__ AB,
        const float* __restrict__ w1, const float* __restrict__ b1,
        const float* __restrict__ w2, uint* __restrict__ Pb, int N) {
    __shared__ float w1s[128 * 32];
    __shared__ float b1s[32], w2s[32];
    __shared__ float aS[4][128], alS[4][128];
    int t = threadIdx.x;
    #pragma unroll
    for (int i = 0; i < 16; i++) w1s[t + i * 256] = w1[t + i * 256];
    if (t < 32) { b1s[t] = b1[t]; w2s[t] = w2[t]; }

    int w = t >> 6, lane = t & 63;
    int node = blockIdx.x * 4 + w;
    bool active = node < N;
    int nclamp = active ? node : (N - 1);
    float2 a = *(const float2*)(AB + (size_t)nclamp * 256 + lane * 2);
    float2 b = *(const float2*)(AB + (size_t)nclamp * 256 + 128 + lane * 2);
    float2 al;
    al.x = a.x + 0.5f * (a.x * a.x - a.x * b.x);
    al.y = a.y + 0.5f * (a.y * a.y - a.y * b.y);
    aS[w][lane * 2] = a.x;   aS[w][lane * 2 + 1] = a.y;
    alS[w][lane * 2] = al.x; alS[w][lane * 2 + 1] = al.y;
    __syncthreads();

    int j = lane & 31;
    const float* src = (lane < 32) ? aS[w] : alS[w];
    float acc = b1s[j];
    #pragma unroll 8
    for (int d = 0; d < 128; ++d) acc = fmaf(src[d], w1s[d * 32 + j], acc);
    float h = tanhf(acc);
    float prod = h * w2s[j];
    #pragma unroll
    for (int off = 1; off < 32; off <<= 1) prod += __shfl_xor(prod, off);
    float eo = __shfl_xor(prod, 32);
    float e0 = (lane < 32) ? prod : eo;
    float e1 = (lane < 32) ? eo : prod;
    float m = fmaxf(e0, e1);
    float p0 = expf(e0 - m), p1 = expf(e1 - m);
    float inv = 1.0f / (p0 + p1);
    float at0 = p0 * inv, at1 = p1 * inv;
    if (active) {
        float px = at0 * a.x + at1 * al.x;
        float py = at0 * a.y + at1 * al.y;
        Pb[(size_t)node * 64 + lane] = packbf2(px, py);
    }
}

// ---------------- batched CSR build ----------------

__global__ void hist_kernel(const int* __restrict__ rows, int4 map,
                            int* __restrict__ cnt, int N, int E) {
    int e = blockIdx.x * 256 + threadIdx.x;
    int s = blockIdx.y;
    if (e >= E) return;
    int r = rows[(size_t)smap(map, s) * E + e];
    atomicAdd(&cnt[s * N + r], 1);
}

// block sums: each block covers 4096 elements of one support's count array
__global__ __launch_bounds__(256) void scan_sums(const int* __restrict__ cnt,
        int* __restrict__ bsum, int N, int NB) {
    __shared__ int wsum[4];
    int s = blockIdx.y, bx = blockIdx.x, t = threadIdx.x;
    int base = bx * 4096 + t * 16;
    const int* c = cnt + (size_t)s * N;
    int ls = 0;
    #pragma unroll
    for (int k = 0; k < 16; k++) { int idx = base + k; if (idx < N) ls += c[idx]; }
    #pragma unroll
    for (int off = 32; off >= 1; off >>= 1) ls += __shfl_xor(ls, off);
    if ((t & 63) == 0) wsum[t >> 6] = ls;
    __syncthreads();
    if (t == 0) bsum[s * NB + bx] = wsum[0] + wsum[1] + wsum[2] + wsum[3];
}

// exclusive scan of block sums per support; writes rp[s][N] = total
__global__ __launch_bounds__(256) void scan_offs(const int* __restrict__ bsum,
        int* __restrict__ boff, int* __restrict__ rp, int NB, int N, int nsup) {
    int t = threadIdx.x;
    if (t < nsup) {
        int run = 0;
        for (int b = 0; b < NB; b++) {
            boff[t * NB + b] = run;
            run += bsum[t * NB + b];
        }
        rp[(size_t)t * (N + 1) + N] = run;
    }
}

// full prefix write: rp (exclusive) and cur (= rp) per support
__global__ __launch_bounds__(256) void scan_write(int* __restrict__ cnt,
        const int* __restrict__ boff, int* __restrict__ rp, int N, int NB) {
    __shared__ int wsum[4];
    int s = blockIdx.y, bx = blockIdx.x, t = threadIdx.x;
    int lane = t & 63, wid = t >> 6;
    int base = bx * 4096 + t * 16;
    int* c = cnt + (size_t)s * N;
    int* rps = rp + (size_t)s * (N + 1);
    int v[16]; int ls = 0;
    #pragma unroll
    for (int k = 0; k < 16; k++) {
        int idx = base + k;
        v[k] = (idx < N) ? c[idx] : 0;
        ls += v[k];
    }
    int incl = ls;
    #pragma unroll
    for (int off = 1; off < 64; off <<= 1) {
        int y = __shfl_up(incl, off);
        if (lane >= off) incl += y;
    }
    if (lane == 63) wsum[wid] = incl;
    __syncthreads();
    int wbase = 0;
    #pragma unroll
    for (int w = 0; w < 4; w++) if (w < wid) wbase += wsum[w];
    int start = boff[s * NB + bx] + wbase + incl - ls;
    #pragma unroll
    for (int k = 0; k < 16; k++) {
        int idx = base + k;
        if (idx < N) { rps[idx] = start; c[idx] = start; }
        start += v[k];
    }
}

__global__ void fill_kernel(const int* __restrict__ rows, const int* __restrict__ cols,
        const float* __restrict__ vals, int4 map, int* __restrict__ cur,
        int2* __restrict__ pk, int N, int E) {
    int e = blockIdx.x * 256 + threadIdx.x;
    int s = blockIdx.y;
    if (e >= E) return;
    size_t off = (size_t)smap(map, s) * E + e;
    int r = rows[off];
    int pos = atomicAdd(&cur[s * N + r], 1);
    pk[(size_t)s * E + pos] = make_int2(cols[off], __float_as_int(vals[off]));
}

// ---------------- fused SpMM kernels ----------------

// t = 0.5*((sA^2-qA) - (sB^2-qB)) over two CSRs, X bf16-packed, out bf16-packed
__global__ __launch_bounds__(256) void spmm_bp2(const int* __restrict__ rpA,
        const int2* __restrict__ pkA, const int* __restrict__ rpB,
        const int2* __restrict__ pkB, const uint* __restrict__ Xb,
        uint* __restrict__ outb, int N) {
    int gt = blockIdx.x * 256 + threadIdx.x;
    int row = gt >> 6, lane = gt & 63;
    if (row >= N) return;
    float sax = 0.f, say = 0.f, qax = 0.f, qay = 0.f;
    float sbx = 0.f, sby = 0.f, qbx = 0.f, qby = 0.f;
    {
        int e = rpA[row], end = rpA[row + 1];
        for (; e + 2 <= end; e += 2) {
            int2 c0 = pkA[e], c1 = pkA[e + 1];
            uint u0 = Xb[(c0.x << 6) + lane];
            uint u1 = Xb[(c1.x << 6) + lane];
            float v0 = __int_as_float(c0.y), v1 = __int_as_float(c1.y);
            float x0 = bfl(u0), y0 = bfh(u0), x1 = bfl(u1), y1 = bfh(u1);
            sax = fmaf(v0, x0, sax); say = fmaf(v0, y0, say);
            qax = fmaf(v0 * x0, x0, qax); qay = fmaf(v0 * y0, y0, qay);
            sax = fmaf(v1, x1, sax); say = fmaf(v1, y1, say);
            qax = fmaf(v1 * x1, x1, qax); qay = fmaf(v1 * y1, y1, qay);
        }
        if (e < end) {
            int2 c0 = pkA[e];
            uint u0 = Xb[(c0.x << 6) + lane];
            float v0 = __int_as_float(c0.y);
            float x0 = bfl(u0), y0 = bfh(u0);
            sax = fmaf(v0, x0, sax); say = fmaf(v0, y0, say);
            qax = fmaf(v0 * x0, x0, qax); qay = fmaf(v0 * y0, y0, qay);
        }
    }
    {
        int e = rpB[row], end = rpB[row + 1];
        for (; e + 2 <= end; e += 2) {
            int2 c0 = pkB[e], c1 = pkB[e + 1];
            uint u0 = Xb[(c0.x << 6) + lane];
            uint u1 = Xb[(c1.x << 6) + lane];
            float v0 = __int_as_float(c0.y), v1 = __int_as_float(c1.y);
            float x0 = bfl(u0), y0 = bfh(u0), x1 = bfl(u1), y1 = bfh(u1);
            sbx = fmaf(v0, x0, sbx); sby = fmaf(v0, y0, sby);
            qbx = fmaf(v0 * x0, x0, qbx); qby = fmaf(v0 * y0, y0, qby);
            sbx = fmaf(v1, x1, sbx); sby = fmaf(v1, y1, sby);
            qbx = fmaf(v1 * x1, x1, qbx); qby = fmaf(v1 * y1, y1, qby);
        }
        if (e < end) {
            int2 c0 = pkB[e];
            uint u0 = Xb[(c0.x << 6) + lane];
            float v0 = __int_as_float(c0.y);
            float x0 = bfl(u0), y0 = bfh(u0);
            sbx = fmaf(v0, x0, sbx); sby = fmaf(v0, y0, sby);
            qbx = fmaf(v0 * x0, x0, qbx); qby = fmaf(v0 * y0, y0, qby);
        }
    }
    float tx = 0.5f * ((sax * sax - qax) - (sbx * sbx - qbx));
    float ty = 0.5f * ((say * say - qay) - (sby * sby - qby));
    outb[((size_t)row << 6) + lane] = packbf2(tx, ty);
}

// out = relu(0.5*spmm0(P) + 0.25*spmm5(t1) + 0.25*spmm6(t2)), fp32 out
__global__ __launch_bounds__(256) void spmm_out(const int* __restrict__ rp0,
        const int2* __restrict__ pk0, const int* __restrict__ rp5,
        const int2* __restrict__ pk5, const int* __restrict__ rp6,
        const int2* __restrict__ pk6, const uint* __restrict__ Pb,
        const uint* __restrict__ t1b, const uint* __restrict__ t2b,
        float* __restrict__ out, int N) {
    int gt = blockIdx.x * 256 + threadIdx.x;
    int row = gt >> 6, lane = gt & 63;
    if (row >= N) return;
    float a0x = 0.f, a0y = 0.f, a5x = 0.f, a5y = 0.f, a6x = 0.f, a6y = 0.f;
    {
        int e = rp0[row], end = rp0[row + 1];
        for (; e + 2 <= end; e += 2) {
            int2 c0 = pk0[e], c1 = pk0[e + 1];
            uint u0 = Pb[(c0.x << 6) + lane];
            uint u1 = Pb[(c1.x << 6) + lane];
            float v0 = __int_as_float(c0.y), v1 = __int_as_float(c1.y);
            a0x = fmaf(v0, bfl(u0), a0x); a0y = fmaf(v0, bfh(u0), a0y);
            a0x = fmaf(v1, bfl(u1), a0x); a0y = fmaf(v1, bfh(u1), a0y);
        }
        if (e < end) {
            int2 c0 = pk0[e];
            uint u0 = Pb[(c0.x << 6) + lane];
            float v0 = __int_as_float(c0.y);
            a0x = fmaf(v0, bfl(u0), a0x); a0y = fmaf(v0, bfh(u0), a0y);
        }
    }
    {
        int e = rp5[row], end = rp5[row + 1];
        for (; e + 2 <= end; e += 2) {
            int2 c0 = pk5[e], c1 = pk5[e + 1];
            uint u0 = t1b[(c0.x << 6) + lane];
            uint u1 = t1b[(c1.x << 6) + lane];
            float v0 = __int_as_float(c0.y), v1 = __int_as_float(c1.y);
            a5x = fmaf(v0, bfl(u0), a5x); a5y = fmaf(v0, bfh(u0), a5y);
            a5x = fmaf(v1, bfl(u1), a5x); a5y = fmaf(v1, bfh(u1), a5y);
        }
        if (e < end) {
            int2 c0 = pk5[e];
            uint u0 = t1b[(c0.x << 6) + lane];
            float v0 = __int_as_float(c0.y);
            a5x = fmaf(v0, bfl(u0), a5x); a5y = fmaf(v0, bfh(u0), a5y);
        }
    }
    {
        int e = rp6[row], end = rp6[row + 1];
        for (; e + 2 <= end; e += 2) {
            int2 c0 = pk6[e], c1 = pk6[e + 1];
            uint u0 = t2b[(c0.x << 6) + lane];
            uint u1 = t2b[(c1.x << 6) + lane];
            float v0 = __int_as_float(c0.y), v1 = __int_as_float(c1.y);
            a6x = fmaf(v0, bfl(u0), a6x); a6y = fmaf(v0, bfh(u0), a6y);
            a6x = fmaf(v1, bfl(u1), a6x); a6y = fmaf(v1, bfh(u1), a6y);
        }
        if (e < end) {
            int2 c0 = pk6[e];
            uint u0 = t2b[(c0.x << 6) + lane];
            float v0 = __int_as_float(c0.y);
            a6x = fmaf(v0, bfl(u0), a6x); a6y = fmaf(v0, bfh(u0), a6y);
        }
    }
    float rx = fmaxf(0.5f * a0x + 0.25f * a5x + 0.25f * a6x, 0.f);
    float ry = fmaxf(0.5f * a0y + 0.25f * a5y + 0.25f * a6y, 0.f);
    *(float2*)(out + ((size_t)row << 7) + (lane << 1)) = make_float2(rx, ry);
}

// ---------------- launch ----------------

extern "C" void kernel_launch(void* const* d_in, const int* in_sizes, int n_in,
                              void* d_out, int out_size, void* d_ws, size_t ws_size,
                              hipStream_t stream) {
    (void)n_in; (void)out_size; (void)ws_size;
    const float* x   = (const float*)d_in[0];
    const float* Wa  = (const float*)d_in[1];
    const float* Wb  = (const float*)d_in[2];
    const float* w1  = (const float*)d_in[4];
    const float* b1  = (const float*)d_in[5];
    const float* w2  = (const float*)d_in[6];
    const int* rows  = (const int*)d_in[7];
    const int* cols  = (const int*)d_in[8];
    const float* vals = (const float*)d_in[9];
    float* out = (float*)d_out;

    const int N = in_sizes[0] / 256;
    const int E = in_sizes[7] / 7;
    const int NB = (N + 4095) / 4096;

    // workspace layout (bytes): Pb,t1b,t2b bf16-packed [N][64] uints; then
    // region R shared by AB (gemm, dead after attn) and pk (4 slots); then ints.
    uint* Pb  = (uint*)d_ws;
    uint* t1b = Pb + (size_t)N * 64;
    uint* t2b = t1b + (size_t)N * 64;
    float* AB = (float*)(t2b + (size_t)N * 64);     // N*256 f32
    int2* pk  = (int2*)AB;                           // 4*E int2 (same size)
    int* rp   = (int*)(AB + (size_t)N * 256);        // 4*(N+1)
    int* cur  = rp + 4 * (size_t)(N + 1);            // 4*N
    int* bsum = cur + 4 * (size_t)N;                 // 4*NB
    int* boff = bsum + 4 * NB;                       // 4*NB

    dim3 b256(256);
    int egrid = (E + 255) / 256;
    int sgrid = (N + 3) / 4;

    // dense front-end
    dim3 ggrid((N + BM - 1) / BM, 2);
    gemm_kernel<<<ggrid, b256, 0, stream>>>(x, Wa, Wb, AB, N);
    attn_kernel<<<sgrid, b256, 0, stream>>>(AB, w1, b1, w2, Pb, N);

    auto build = [&](int4 map, int nsup) {
        hipMemsetAsync(cur, 0, (size_t)nsup * N * sizeof(int), stream);
        hist_kernel<<<dim3(egrid, nsup), b256, 0, stream>>>(rows, map, cur, N, E);
        scan_sums<<<dim3(NB, nsup), b256, 0, stream>>>(cur, bsum, N, NB);
        scan_offs<<<1, b256, 0, stream>>>(bsum, boff, rp, NB, N, nsup);
        scan_write<<<dim3(NB, nsup), b256, 0, stream>>>(cur, boff, rp, N, NB);
        fill_kernel<<<dim3(egrid, nsup), b256, 0, stream>>>(rows, cols, vals, map, cur, pk, N, E);
    };

    const int NP1 = N + 1;

    // group A: slots {1,3,2,4}  (AB is dead now; pk aliases it)
    build(make_int4(1, 3, 2, 4), 4);
    spmm_bp2<<<sgrid, b256, 0, stream>>>(rp + 0 * NP1, pk + 0 * (size_t)E,
                                         rp + 1 * NP1, pk + 1 * (size_t)E, Pb, t1b, N);
    spmm_bp2<<<sgrid, b256, 0, stream>>>(rp + 2 * NP1, pk + 2 * (size_t)E,
                                         rp + 3 * NP1, pk + 3 * (size_t)E, Pb, t2b, N);

    // group B: slots {0,5,6}
    build(make_int4(0, 5, 6, 6), 3);
    spmm_out<<<sgrid, b256, 0, stream>>>(rp + 0 * NP1, pk + 0 * (size_t)E,
                                         rp + 1 * NP1, pk + 1 * (size_t)E,
                                         rp + 2 * NP1, pk + 2 * (size_t)E,
                                         Pb, t1b, t2b, out, N);
}